// Round 5
// baseline (459.415 us; speedup 1.0000x reference)
//
#include <hip/hip_runtime.h>

// SJLT projection: out[b, idx[d,j]] += x[b,d] * sign(d,j), * 1/sqrt(4)
// B=64, D=524288, P=8192, C=4.
//
// R4 post-mortem: scatter_kernel = 82us with 113MB HBM writes for an 8MB
// payload (random 4B stores don't write-combine). R5:
//  - entries stored via atomicExch (executes+allocates in home-XCD L2;
//    8MB region fits aggregate L2 -> write-combined evictions only)
//  - hist fused into transpose (one fewer 8MB pass; atomics overlap BW)
//  - scan rewritten shfl-based (2 barriers instead of 20)
//  - gather: unrolled full-chunk path (no predication -> batched loads)

constexpr int BATCH = 64;
constexpr int DIM   = 524288;
constexpr int PROJ  = 8192;
constexpr int NENT  = DIM * 4;          // 2,097,152 entries

// ------------------------------------------------ transpose + histogram
__device__ __forceinline__ uint32_t f2bf(float f) {   // RNE f32 -> bf16 bits
    uint32_t u = __float_as_uint(f);
    return (u + 0x7fffu + ((u >> 16) & 1u)) >> 16;
}

// x (64 x DIM f32) -> xT (DIM x 32 u32); u32 k = bf16(x[2k][d]*.5) | bf16(x[2k+1][d]*.5)<<16
// wave 0 additionally histograms this block's 64 d's into cnt[] (global int atomics).
__global__ __launch_bounds__(256) void transpose_hist_kernel(
    const float* __restrict__ x, const int4* __restrict__ idx4,
    uint32_t* __restrict__ xT, uint32_t* __restrict__ cnt)
{
    __shared__ float tile[64][65];
    const int d0   = blockIdx.x * 64;
    const int lane = threadIdx.x & 63;
    const int q    = threadIdx.x >> 6;      // wave id 0..3
#pragma unroll
    for (int r = 0; r < 16; ++r) {
        int b = r * 4 + q;
        tile[b][lane] = x[(size_t)b * DIM + d0 + lane];
    }
    if (threadIdx.x < 64) {                 // fused histogram (wave 0)
        int4 iv = idx4[d0 + threadIdx.x];
        atomicAdd(&cnt[iv.x], 1u);
        atomicAdd(&cnt[iv.y], 1u);
        atomicAdd(&cnt[iv.z], 1u);
        atomicAdd(&cnt[iv.w], 1u);
    }
    __syncthreads();
    const int k   = threadIdx.x & 31;       // u32 index in xT row
    const int dl0 = threadIdx.x >> 5;       // 0..7
#pragma unroll
    for (int pass = 0; pass < 8; ++pass) {
        int dl = pass * 8 + dl0;
        uint32_t lo = f2bf(tile[2 * k + 0][dl] * 0.5f);
        uint32_t hi = f2bf(tile[2 * k + 1][dl] * 0.5f);
        xT[(size_t)(d0 + dl) * 32 + k] = lo | (hi << 16);
    }
}

// ---------------------------------------------------------------- scan
// exclusive prefix sum of cnt[8192] -> cur[8192]; 256 threads, 32 each
__global__ __launch_bounds__(256) void scan_kernel(
    const uint32_t* __restrict__ cnt, uint32_t* __restrict__ cur)
{
    __shared__ uint32_t wsum[4];
    const int t    = threadIdx.x;
    const int lane = t & 63;
    uint32_t c[32];
    uint32_t s = 0;
#pragma unroll
    for (int i = 0; i < 32; ++i) { c[i] = cnt[t * 32 + i]; s += c[i]; }
    uint32_t v = s;                          // inclusive scan of thread sums
#pragma unroll
    for (int off = 1; off < 64; off <<= 1) {
        uint32_t u = __shfl_up(v, off);
        if (lane >= off) v += u;
    }
    if (lane == 63) wsum[t >> 6] = v;
    __syncthreads();
    uint32_t wb = 0;
    for (int w0 = 0; w0 < (t >> 6); ++w0) wb += wsum[w0];
    uint32_t base = wb + v - s;              // exclusive base for this thread
#pragma unroll
    for (int i = 0; i < 32; ++i) { cur[t * 32 + i] = base; base += c[i]; }
}

// -------------------------------------------------------------- scatter
__global__ __launch_bounds__(256) void scatter_kernel(
    const int4* __restrict__ idx4, const int4* __restrict__ sgn4,
    uint32_t* __restrict__ cur, uint32_t* __restrict__ entries)
{
    int d = blockIdx.x * 256 + threadIdx.x;
    int4 iv = idx4[d];
    int4 sv = sgn4[d];
    const uint32_t dv = (uint32_t)d << 1;
    uint32_t slot;
    // atomicExch so the store executes in (and allocates) the home L2 line:
    // kills R4's 14x partial-line write-through amplification
    slot = atomicAdd(&cur[iv.x], 1u); atomicExch(&entries[slot], dv | (uint32_t)(sv.x & 1));
    slot = atomicAdd(&cur[iv.y], 1u); atomicExch(&entries[slot], dv | (uint32_t)(sv.y & 1));
    slot = atomicAdd(&cur[iv.z], 1u); atomicExch(&entries[slot], dv | (uint32_t)(sv.z & 1));
    slot = atomicAdd(&cur[iv.w], 1u); atomicExch(&entries[slot], dv | (uint32_t)(sv.w & 1));
}

// --------------------------------------------------------------- gather
__global__ __launch_bounds__(256) void gather_kernel(
    const uint32_t* __restrict__ entries, const uint32_t* __restrict__ cnt,
    const uint32_t* __restrict__ endp, const uint32_t* __restrict__ xT,
    float* __restrict__ out)
{
    const int w    = threadIdx.x >> 6;
    const int lane = threadIdx.x & 63;
    const int p    = blockIdx.x * 4 + w;
    const uint32_t n  = cnt[p];
    const uint32_t e0 = endp[p] - n;

    const int half = lane >> 5;     // 0: even entries, 1: odd entries
    const int k    = lane & 31;     // u32 index within xT row (2 batch elems)
    float acc0 = 0.f, acc1 = 0.f;

    uint32_t base = 0;
    for (; base + 64 <= n; base += 64) {            // full chunks: no predication
        uint32_t ev = entries[e0 + base + lane];
#pragma unroll
        for (int t = 0; t < 64; t += 2) {
            uint32_t eA = __shfl(ev, t);
            uint32_t eB = __shfl(ev, t + 1);
            uint32_t sel = half ? eB : eA;
            uint32_t d = sel >> 1;
            uint32_t u = xT[(size_t)d * 32 + k];    // 128B/half-wave, one line
            u ^= (sel & 1u) ? 0u : 0x80008000u;     // s=0 -> negate both halves
            acc0 += __uint_as_float(u << 16);           // b = 2k
            acc1 += __uint_as_float(u & 0xffff0000u);   // b = 2k+1
        }
    }
    const uint32_t rem = n - base;
    if (rem) {
        uint32_t gi = base + (uint32_t)lane;
        uint32_t ev = (gi < n) ? entries[e0 + gi] : 0u;
        for (uint32_t t = 0; t < rem; t += 2) {
            uint32_t eA = __shfl(ev, (int)t);
            uint32_t eB = __shfl(ev, (int)t + 1);
            uint32_t sel   = half ? eB : eA;
            bool     valid = (base + t + (uint32_t)half) < n;
            sel = valid ? sel : 1u;
            uint32_t d = sel >> 1;
            uint32_t u = xT[(size_t)d * 32 + k];
            u ^= (sel & 1u) ? 0u : 0x80008000u;
            u  = valid ? u : 0u;
            acc0 += __uint_as_float(u << 16);
            acc1 += __uint_as_float(u & 0xffff0000u);
        }
    }
    acc0 += __shfl_xor(acc0, 32);
    acc1 += __shfl_xor(acc1, 32);
    if (half == 0) {
        out[(size_t)(2 * k + 0) * PROJ + p] = acc0;
        out[(size_t)(2 * k + 1) * PROJ + p] = acc1;
    }
}

// ------------------------------------------------- fallback (R3 scatter)
__device__ __forceinline__ void lds_fadd(uint32_t byte_addr, float v) {
    asm volatile("ds_add_f32 %0, %1" :: "v"(byte_addr), "v"(v) : "memory");
}
__device__ __forceinline__ void lds_fadd_off32k(uint32_t byte_addr, float v) {
    asm volatile("ds_add_f32 %0, %1 offset:32768" :: "v"(byte_addr), "v"(v) : "memory");
}

__global__ __launch_bounds__(1024) void sjlt_scatter(
    const float* __restrict__ x, const int4* __restrict__ idx4,
    const int4* __restrict__ sgn4, float* __restrict__ out)
{
    __shared__ float acc[4 * PROJ];
    for (int i = threadIdx.x; i < 4 * PROJ; i += 1024) acc[i] = 0.0f;
    __syncthreads();
    const int row0 = blockIdx.y * 4;
    const int dbeg = blockIdx.x * (DIM / 16);
    const uint32_t accBase = (uint32_t)(uintptr_t)(&acc[0]);
    const float* xr0 = x + (size_t)(row0 + 0) * DIM;
    const float* xr1 = x + (size_t)(row0 + 1) * DIM;
    const float* xr2 = x + (size_t)(row0 + 2) * DIM;
    const float* xr3 = x + (size_t)(row0 + 3) * DIM;
    for (int d = dbeg + (int)threadIdx.x; d < dbeg + DIM / 16; d += 1024) {
        const int4 iv = idx4[d];
        const int4 sv = sgn4[d];
        const uint32_t u0 = __float_as_uint(xr0[d]);
        const uint32_t u1 = __float_as_uint(xr1[d]);
        const uint32_t u2 = __float_as_uint(xr2[d]);
        const uint32_t u3 = __float_as_uint(xr3[d]);
        const int p[4] = {iv.x, iv.y, iv.z, iv.w};
        const int s[4] = {sv.x, sv.y, sv.z, sv.w};
#pragma unroll
        for (int j = 0; j < 4; ++j) {
            const uint32_t flip = (uint32_t)(s[j] ^ 1) << 31;
            const uint32_t a01  = accBase + ((uint32_t)p[j] << 2);
            const uint32_t a23  = a01 + 2u * 32768u;
            lds_fadd        (a01, __uint_as_float(u0 ^ flip));
            lds_fadd_off32k (a01, __uint_as_float(u1 ^ flip));
            lds_fadd        (a23, __uint_as_float(u2 ^ flip));
            lds_fadd_off32k (a23, __uint_as_float(u3 ^ flip));
        }
    }
    __syncthreads();
    for (int i = threadIdx.x; i < 4 * PROJ; i += 1024) {
        const int r  = i >> 13;
        const int pp = i & (PROJ - 1);
        unsafeAtomicAdd(&out[(size_t)(row0 + r) * PROJ + pp], acc[i] * 0.5f);
    }
}

// --------------------------------------------------------------- launch
extern "C" void kernel_launch(void* const* d_in, const int* in_sizes, int n_in,
                              void* d_out, int out_size, void* d_ws, size_t ws_size,
                              hipStream_t stream) {
    const float* x   = (const float*)d_in[0];
    const int4*  idx = (const int4*) d_in[1];
    const int4*  sgn = (const int4*) d_in[2];
    float*       out = (float*)d_out;

    const size_t need = ((size_t)PROJ + PROJ + NENT + (size_t)DIM * 32) * 4;  // 75,563,008 B
    if (ws_size >= need) {
        uint32_t* cnt     = (uint32_t*)d_ws;
        uint32_t* cur     = cnt + PROJ;
        uint32_t* entries = cur + PROJ;
        uint32_t* xT      = entries + NENT;

        hipMemsetAsync(cnt, 0, PROJ * sizeof(uint32_t), stream);
        transpose_hist_kernel<<<DIM / 64, 256, 0, stream>>>(x, idx, xT, cnt);
        scan_kernel          <<<1,        256, 0, stream>>>(cnt, cur);
        scatter_kernel       <<<DIM / 256, 256, 0, stream>>>(idx, sgn, cur, entries);
        gather_kernel        <<<PROJ / 4, 256, 0, stream>>>(entries, cnt, cur, xT, out);
    } else {
        // ws too small: R3 LDS-scatter path (passes at ~830 us)
        hipMemsetAsync(d_out, 0, (size_t)out_size * sizeof(float), stream);
        dim3 grid(16, 16);
        sjlt_scatter<<<grid, 1024, 0, stream>>>(x, idx, sgn, out);
    }
}

// Round 6
// 400.179 us; speedup vs baseline: 1.1480x; 1.1480x over previous
//
#include <hip/hip_runtime.h>

// SJLT projection: out[b, idx[d,j]] += x[b,d] * sign(d,j), * 1/sqrt(4)
// B=64, D=524288, P=8192, C=4.
//
// Model so far (R1-R5):
//  - LDS fp atomics: ~3.2 cyc/LANE (per-lane serialized) -> never use.
//  - Random 4B global stores/atomics: 64B HBM write EACH (no-write-allocate
//    L2). R6 tests whether memset pretouch converts them to store-hits.
//  - CSR+gather structure: 432us best (R4).
// R6: scatter = plain stores + entries pretouch; gather = scalar-broadcast
// entries (s_load, no shfl), 8-entry unroll.

constexpr int BATCH = 64;
constexpr int DIM   = 524288;
constexpr int PROJ  = 8192;
constexpr int NENT  = DIM * 4;          // 2,097,152 entries

// ------------------------------------------------ transpose + histogram
__device__ __forceinline__ uint32_t f2bf(float f) {   // RNE f32 -> bf16 bits
    uint32_t u = __float_as_uint(f);
    return (u + 0x7fffu + ((u >> 16) & 1u)) >> 16;
}

// x (64 x DIM f32) -> xT (DIM x 32 u32); u32 k = bf16(x[2k][d]*.5) | bf16(x[2k+1][d]*.5)<<16
// wave 0 additionally histograms this block's 64 d's into cnt[].
__global__ __launch_bounds__(256) void transpose_hist_kernel(
    const float* __restrict__ x, const int4* __restrict__ idx4,
    uint32_t* __restrict__ xT, uint32_t* __restrict__ cnt)
{
    __shared__ float tile[64][65];
    const int d0   = blockIdx.x * 64;
    const int lane = threadIdx.x & 63;
    const int q    = threadIdx.x >> 6;      // wave id 0..3
#pragma unroll
    for (int r = 0; r < 16; ++r) {
        int b = r * 4 + q;
        tile[b][lane] = x[(size_t)b * DIM + d0 + lane];
    }
    if (threadIdx.x < 64) {                 // fused histogram (wave 0)
        int4 iv = idx4[d0 + threadIdx.x];
        atomicAdd(&cnt[iv.x], 1u);
        atomicAdd(&cnt[iv.y], 1u);
        atomicAdd(&cnt[iv.z], 1u);
        atomicAdd(&cnt[iv.w], 1u);
    }
    __syncthreads();
    const int k   = threadIdx.x & 31;       // u32 index in xT row
    const int dl0 = threadIdx.x >> 5;       // 0..7
#pragma unroll
    for (int pass = 0; pass < 8; ++pass) {
        int dl = pass * 8 + dl0;
        uint32_t lo = f2bf(tile[2 * k + 0][dl] * 0.5f);
        uint32_t hi = f2bf(tile[2 * k + 1][dl] * 0.5f);
        xT[(size_t)(d0 + dl) * 32 + k] = lo | (hi << 16);
    }
}

// ---------------------------------------------------------------- scan
// exclusive prefix sum of cnt[8192] -> cur[8192]; 256 threads, 32 each
__global__ __launch_bounds__(256) void scan_kernel(
    const uint32_t* __restrict__ cnt, uint32_t* __restrict__ cur)
{
    __shared__ uint32_t wsum[4];
    const int t    = threadIdx.x;
    const int lane = t & 63;
    uint32_t c[32];
    uint32_t s = 0;
#pragma unroll
    for (int i = 0; i < 32; ++i) { c[i] = cnt[t * 32 + i]; s += c[i]; }
    uint32_t v = s;                          // inclusive scan of thread sums
#pragma unroll
    for (int off = 1; off < 64; off <<= 1) {
        uint32_t u = __shfl_up(v, off);
        if (lane >= off) v += u;
    }
    if (lane == 63) wsum[t >> 6] = v;
    __syncthreads();
    uint32_t wb = 0;
    for (int w0 = 0; w0 < (t >> 6); ++w0) wb += wsum[w0];
    uint32_t base = wb + v - s;              // exclusive base for this thread
#pragma unroll
    for (int i = 0; i < 32; ++i) { cur[t * 32 + i] = base; base += c[i]; }
}

// -------------------------------------------------------------- scatter
// plain 4B stores (R4 behavior); entries region is memset-pretouched so
// stores may hit resident L2 lines instead of no-allocate write-through.
__global__ __launch_bounds__(256) void scatter_kernel(
    const int4* __restrict__ idx4, const int4* __restrict__ sgn4,
    uint32_t* __restrict__ cur, uint32_t* __restrict__ entries)
{
    int d = blockIdx.x * 256 + threadIdx.x;
    int4 iv = idx4[d];
    int4 sv = sgn4[d];
    const uint32_t dv = (uint32_t)d << 1;
    uint32_t slot;
    slot = atomicAdd(&cur[iv.x], 1u); entries[slot] = dv | (uint32_t)(sv.x & 1);
    slot = atomicAdd(&cur[iv.y], 1u); entries[slot] = dv | (uint32_t)(sv.y & 1);
    slot = atomicAdd(&cur[iv.z], 1u); entries[slot] = dv | (uint32_t)(sv.z & 1);
    slot = atomicAdd(&cur[iv.w], 1u); entries[slot] = dv | (uint32_t)(sv.w & 1);
}

// --------------------------------------------------------------- gather
// wave per p; entry stream is wave-uniform -> scalar loads (no shfl).
__global__ __launch_bounds__(256) void gather_kernel(
    const uint32_t* __restrict__ entries, const uint32_t* __restrict__ cnt,
    const uint32_t* __restrict__ endp, const uint32_t* __restrict__ xT,
    float* __restrict__ out)
{
    const int w    = threadIdx.x >> 6;
    const int lane = threadIdx.x & 63;
    const int p    = __builtin_amdgcn_readfirstlane(blockIdx.x * 4 + w);
    const uint32_t n  = __builtin_amdgcn_readfirstlane(cnt[p]);
    const uint32_t e0 = __builtin_amdgcn_readfirstlane(endp[p] - n);

    const int half = lane >> 5;     // 0: even entries, 1: odd entries
    const int k    = lane & 31;     // u32 index within xT row (2 batch elems)
    float acc0 = 0.f, acc1 = 0.f;

    uint32_t base = 0;
    for (; base + 8 <= n; base += 8) {       // uniform indices -> s_load
        uint32_t e8[8];
#pragma unroll
        for (int t = 0; t < 8; ++t) e8[t] = entries[e0 + base + t];
#pragma unroll
        for (int t = 0; t < 8; t += 2) {
            uint32_t sel = half ? e8[t + 1] : e8[t];
            uint32_t u = xT[(size_t)(sel >> 1) * 32 + k];   // 128B/half-wave
            u ^= (sel & 1u) ? 0u : 0x80008000u;             // s=0 -> negate pair
            acc0 += __uint_as_float(u << 16);               // b = 2k
            acc1 += __uint_as_float(u & 0xffff0000u);       // b = 2k+1
        }
    }
    for (; base < n; base += 2) {            // tail (<8 entries)
        uint32_t eA = entries[e0 + base];
        uint32_t eB = (base + 1 < n) ? entries[e0 + base + 1] : 0u;
        uint32_t sel   = half ? eB : eA;
        bool     valid = (base + (uint32_t)half) < n;
        uint32_t u = 0u;
        if (valid) {
            u = xT[(size_t)(sel >> 1) * 32 + k];
            u ^= (sel & 1u) ? 0u : 0x80008000u;
        }
        acc0 += __uint_as_float(u << 16);
        acc1 += __uint_as_float(u & 0xffff0000u);
    }
    acc0 += __shfl_xor(acc0, 32);
    acc1 += __shfl_xor(acc1, 32);
    if (half == 0) {
        out[(size_t)(2 * k + 0) * PROJ + p] = acc0;
        out[(size_t)(2 * k + 1) * PROJ + p] = acc1;
    }
}

// ------------------------------------------------- fallback (R3 scatter)
__device__ __forceinline__ void lds_fadd(uint32_t byte_addr, float v) {
    asm volatile("ds_add_f32 %0, %1" :: "v"(byte_addr), "v"(v) : "memory");
}
__device__ __forceinline__ void lds_fadd_off32k(uint32_t byte_addr, float v) {
    asm volatile("ds_add_f32 %0, %1 offset:32768" :: "v"(byte_addr), "v"(v) : "memory");
}

__global__ __launch_bounds__(1024) void sjlt_scatter(
    const float* __restrict__ x, const int4* __restrict__ idx4,
    const int4* __restrict__ sgn4, float* __restrict__ out)
{
    __shared__ float acc[4 * PROJ];
    for (int i = threadIdx.x; i < 4 * PROJ; i += 1024) acc[i] = 0.0f;
    __syncthreads();
    const int row0 = blockIdx.y * 4;
    const int dbeg = blockIdx.x * (DIM / 16);
    const uint32_t accBase = (uint32_t)(uintptr_t)(&acc[0]);
    const float* xr0 = x + (size_t)(row0 + 0) * DIM;
    const float* xr1 = x + (size_t)(row0 + 1) * DIM;
    const float* xr2 = x + (size_t)(row0 + 2) * DIM;
    const float* xr3 = x + (size_t)(row0 + 3) * DIM;
    for (int d = dbeg + (int)threadIdx.x; d < dbeg + DIM / 16; d += 1024) {
        const int4 iv = idx4[d];
        const int4 sv = sgn4[d];
        const uint32_t u0 = __float_as_uint(xr0[d]);
        const uint32_t u1 = __float_as_uint(xr1[d]);
        const uint32_t u2 = __float_as_uint(xr2[d]);
        const uint32_t u3 = __float_as_uint(xr3[d]);
        const int p[4] = {iv.x, iv.y, iv.z, iv.w};
        const int s[4] = {sv.x, sv.y, sv.z, sv.w};
#pragma unroll
        for (int j = 0; j < 4; ++j) {
            const uint32_t flip = (uint32_t)(s[j] ^ 1) << 31;
            const uint32_t a01  = accBase + ((uint32_t)p[j] << 2);
            const uint32_t a23  = a01 + 2u * 32768u;
            lds_fadd        (a01, __uint_as_float(u0 ^ flip));
            lds_fadd_off32k (a01, __uint_as_float(u1 ^ flip));
            lds_fadd        (a23, __uint_as_float(u2 ^ flip));
            lds_fadd_off32k (a23, __uint_as_float(u3 ^ flip));
        }
    }
    __syncthreads();
    for (int i = threadIdx.x; i < 4 * PROJ; i += 1024) {
        const int r  = i >> 13;
        const int pp = i & (PROJ - 1);
        unsafeAtomicAdd(&out[(size_t)(row0 + r) * PROJ + pp], acc[i] * 0.5f);
    }
}

// --------------------------------------------------------------- launch
extern "C" void kernel_launch(void* const* d_in, const int* in_sizes, int n_in,
                              void* d_out, int out_size, void* d_ws, size_t ws_size,
                              hipStream_t stream) {
    const float* x   = (const float*)d_in[0];
    const int4*  idx = (const int4*) d_in[1];
    const int4*  sgn = (const int4*) d_in[2];
    float*       out = (float*)d_out;

    const size_t need = ((size_t)PROJ + PROJ + NENT + (size_t)DIM * 32) * 4;  // 75,563,008 B
    if (ws_size >= need) {
        uint32_t* cnt     = (uint32_t*)d_ws;
        uint32_t* cur     = cnt + PROJ;
        uint32_t* entries = cur + PROJ;
        uint32_t* xT      = entries + NENT;

        hipMemsetAsync(cnt, 0, PROJ * sizeof(uint32_t), stream);
        // pretouch: full-line writes may leave entries lines L2-resident so
        // scatter's 4B stores hit instead of no-allocate write-through
        hipMemsetAsync(entries, 0, (size_t)NENT * sizeof(uint32_t), stream);
        transpose_hist_kernel<<<DIM / 64,  256, 0, stream>>>(x, idx, xT, cnt);
        scan_kernel          <<<1,         256, 0, stream>>>(cnt, cur);
        scatter_kernel       <<<DIM / 256, 256, 0, stream>>>(idx, sgn, cur, entries);
        gather_kernel        <<<PROJ / 4,  256, 0, stream>>>(entries, cnt, cur, xT, out);
    } else {
        // ws too small: R3 LDS-scatter path (passes at ~830 us)
        hipMemsetAsync(d_out, 0, (size_t)out_size * sizeof(float), stream);
        dim3 grid(16, 16);
        sjlt_scatter<<<grid, 1024, 0, stream>>>(x, idx, sgn, out);
    }
}